// Round 2
// baseline (495.234 us; speedup 1.0000x reference)
//
#include <hip/hip_runtime.h>

// B=256, T=2048, F=64, U=10 LSTM (Keras gates i,f,g,o; softsign cell act).
// R2: TWO batch elements per block (grid=128). Wave0 = scan, interleaving two
// independent recurrence chains (same Rc, separate h/c registers) so the two
// dependent chains hide each other's stalls on the otherwise-solo scan SIMD.
// Waves 1-3 = producers: z = x@W+bias for BOTH batches, one CH=32-step chunk
// ahead, packed as float2 {zA,zB} in LDS (scan seeds arrive via one
// ds_read_b64). x chunks DMA'd 2 ahead via global_load_lds. Activation uses a
// shared-rcp trick: t = gate==2 ? |zz| : exp2(zz); r = rcp(1+t);
// a = gate==2 ? zz*r : r  -- one fewer v_rcp + v_add per step than computing
// sigmoid and softsign separately (sigmoid cols pre-scaled by -log2e).
#define B_ 256
#define T_ 2048
#define F_ 64
#define U_ 10
#define G_ 40
#define CH 32          // timesteps per chunk (halved: dual-batch LDS budget)
#define NCH (T_ / CH)  // 64
#define NLOG2E (-1.44269504088896340736f)

__device__ __forceinline__ float rcp_f(float x) { return __builtin_amdgcn_rcpf(x); }
__device__ __forceinline__ float exp2_f(float x) { return __builtin_amdgcn_exp2f(x); }
__device__ __forceinline__ float rdlane_f(float v, int l) {
  return __int_as_float(__builtin_amdgcn_readlane(__float_as_int(v), l));
}
template <int CTRL>
__device__ __forceinline__ float qbcast(float v) {  // quad_perm broadcast
  return __int_as_float(
      __builtin_amdgcn_update_dpp(0, __float_as_int(v), CTRL, 0xF, 0xF, true));
}
__device__ __forceinline__ void gload_lds16(const float* g, float* l) {
  // lane i's 16B lands at l + i*16; g is per-lane (contiguous across wave)
  __builtin_amdgcn_global_load_lds(
      (const __attribute__((address_space(1))) void*)g,
      (__attribute__((address_space(3))) void*)l, 16, 0, 0);
}

__global__ __launch_bounds__(256, 1) void lstm_fused(
    const float* __restrict__ x, const float* __restrict__ W,
    const float* __restrict__ R, const float* __restrict__ bias,
    const float* __restrict__ dw, const float* __restrict__ db,
    float* __restrict__ out) {
  __shared__ float xb[2][2][CH * F_];   // [buf][batch][2048] = 32 KB (DMA dst)
  __shared__ float2 zbuf[2][CH * G_];   // [buf][t*G+col] {zA,zB} = 20 KB
  const int blk = blockIdx.x;           // 0..127 -> batches 2*blk, 2*blk+1
  const int tid = threadIdx.x;
  const int wave = tid >> 6;
  const int lane = tid & 63;
  const float* xA = x + (size_t)(2 * blk) * T_ * F_;
  const float* xBp = x + (size_t)(2 * blk + 1) * T_ * F_;

  if (wave == 0) {
    // ---------------- scan wave: two interleaved chains ----------------
    __builtin_amdgcn_s_setprio(3);
    const int L = (lane < G_) ? lane : (G_ - 1);
    const int u = L >> 2, gate = L & 3;
    const int col = gate * U_ + u;
    const float sc = (gate == 2) ? 1.f : NLOG2E;  // sigmoid cols scaled
    float Rc[U_];
    #pragma unroll
    for (int j = 0; j < U_; ++j) Rc[j] = R[j * G_ + col] * sc;
    const float dwu = dw[u];
    const float db0 = db[0];
    float hA = 0.f, cA = 0.f, hB = 0.f, cB = 0.f;

    // one timestep for BOTH batches; z2 = {zA,zB} seeds (pre-scaled)
    auto step2 = [&](float2 z2) {
      float a0 = rdlane_f(hA, 0),  b0 = rdlane_f(hB, 0);
      float a1 = rdlane_f(hA, 4),  b1 = rdlane_f(hB, 4);
      float a2 = rdlane_f(hA, 8),  b2 = rdlane_f(hB, 8);
      float a3 = rdlane_f(hA, 12), b3 = rdlane_f(hB, 12);
      float a4 = rdlane_f(hA, 16), b4 = rdlane_f(hB, 16);
      float a5 = rdlane_f(hA, 20), b5 = rdlane_f(hB, 20);
      float a6 = rdlane_f(hA, 24), b6 = rdlane_f(hB, 24);
      float a7 = rdlane_f(hA, 28), b7 = rdlane_f(hB, 28);
      float a8 = rdlane_f(hA, 32), b8 = rdlane_f(hB, 32);
      float a9 = rdlane_f(hA, 36), b9 = rdlane_f(hB, 36);
      // 4-chain matvec per batch, interleaved
      float qa0 = fmaf(a0, Rc[0], z2.x);  float qb0 = fmaf(b0, Rc[0], z2.y);
      qa0 = fmaf(a1, Rc[1], qa0);         qb0 = fmaf(b1, Rc[1], qb0);
      qa0 = fmaf(a2, Rc[2], qa0);         qb0 = fmaf(b2, Rc[2], qb0);
      float qa1 = a3 * Rc[3];             float qb1 = b3 * Rc[3];
      qa1 = fmaf(a4, Rc[4], qa1);         qb1 = fmaf(b4, Rc[4], qb1);
      qa1 = fmaf(a5, Rc[5], qa1);         qb1 = fmaf(b5, Rc[5], qb1);
      float qa2 = a6 * Rc[6];             float qb2 = b6 * Rc[6];
      qa2 = fmaf(a7, Rc[7], qa2);         qb2 = fmaf(b7, Rc[7], qb2);
      float qa3 = a8 * Rc[8];             float qb3 = b8 * Rc[8];
      qa3 = fmaf(a9, Rc[9], qa3);         qb3 = fmaf(b9, Rc[9], qb3);
      float zzA = (qa0 + qa2) + (qa1 + qa3);
      float zzB = (qb0 + qb2) + (qb1 + qb3);
      // shared-rcp activation: sigmoid lanes zz = -log2e*z -> e^{-z}=exp2(zz)
      float eA = exp2_f(zzA);             float eB = exp2_f(zzB);
      float tA = (gate == 2) ? __builtin_fabsf(zzA) : eA;
      float tB = (gate == 2) ? __builtin_fabsf(zzB) : eB;
      float rA = rcp_f(1.f + tA);         float rB = rcp_f(1.f + tB);
      float aAct = (gate == 2) ? zzA * rA : rA;
      float bAct = (gate == 2) ? zzB * rB : rB;
      float aiA = qbcast<0x00>(aAct), aiB = qbcast<0x00>(bAct);
      float afA = qbcast<0x55>(aAct), afB = qbcast<0x55>(bAct);
      float agA = qbcast<0xAA>(aAct), agB = qbcast<0xAA>(bAct);
      float aoA = qbcast<0xFF>(aAct), aoB = qbcast<0xFF>(bAct);
      cA = fmaf(afA, cA, aiA * agA);      cB = fmaf(afB, cB, aiB * agB);
      float ocA = aoA * cA;               float ocB = aoB * cB;
      float denA = 1.f + __builtin_fabsf(cA);
      float denB = 1.f + __builtin_fabsf(cB);
      hA = ocA * rcp_f(denA);             hB = ocB * rcp_f(denB);
    };

    __syncthreads();  // B-pre1: x(0),x(1) DMA complete
    __syncthreads();  // B-pre2: z(0) produced
    for (int cc = 0; cc < NCH; ++cc) {
      const float2* zp = zbuf[cc & 1] + L;
      // prime two 4-step groups (8-step prefetch distance)
      float2 zA0 = zp[0 * G_], zA1 = zp[1 * G_], zA2 = zp[2 * G_], zA3 = zp[3 * G_];
      float2 zB0 = zp[4 * G_], zB1 = zp[5 * G_], zB2 = zp[6 * G_], zB3 = zp[7 * G_];
      #pragma unroll 1
      for (int pr = 0; pr < 4; ++pr) {      // 4 pairs x 8 = 32 steps
        const float2* zn = zp + 8 * G_;
        const float2* zs = (pr < 3) ? zn : zp;  // clamp: last refill unused
        float2 s0 = zA0, s1 = zA1, s2 = zA2, s3 = zA3;
        zA0 = zs[0 * G_]; zA1 = zs[1 * G_];
        zA2 = zs[2 * G_]; zA3 = zs[3 * G_];
        step2(s0); step2(s1); step2(s2); step2(s3);
        float2 d0 = zB0, d1 = zB1, d2 = zB2, d3 = zB3;
        zB0 = zs[4 * G_]; zB1 = zs[5 * G_];
        zB2 = zs[6 * G_]; zB3 = zs[7 * G_];
        step2(d0); step2(d1); step2(d2); step2(d3);
        zp = zn;
      }
      __syncthreads();  // B(cc)
    }
    // epilogue: logit = sum_u h[u]*dw[u] + db; out = sigmoid(logit)
    float pA = hA * dwu, pB = hB * dwu;
    float lgA = db0, lgB = db0;
    #pragma unroll
    for (int j = 0; j < U_; ++j) {
      lgA += rdlane_f(pA, 4 * j);
      lgB += rdlane_f(pB, 4 * j);
    }
    if (lane == 0) {
      out[2 * blk] = rcp_f(1.f + __expf(-lgA));
      out[2 * blk + 1] = rcp_f(1.f + __expf(-lgB));
    }
  } else {
    // ---------------- producer waves (1..3) ----------------
    const int p0 = tid - 64;                 // 0..191
    const int p = (p0 < 160) ? p0 : 159;
    const bool act = (p0 < 160);
    const int s = p % G_;                    // column slot 0..39
    const int tsl = p / G_;                  // t-slot 0..3
    const int u = s >> 2, gate = s & 3;
    const int col = gate * U_ + u;
    const int pw = wave - 1;                 // 0..2
    const float scp = (gate == 2) ? 1.f : NLOG2E;  // pre-scale sigmoid cols
    float wc[F_];
    #pragma unroll
    for (int k = 0; k < F_; ++k) wc[k] = W[k * G_ + col];
    const float bcol = bias[col];

    auto load_x = [&](int cx) {  // DMA x chunk cx for BOTH batches (16 KB)
      const size_t co = (size_t)cx * CH * F_;
      float* ldst = &xb[cx & 1][0][0];       // batch B region follows A
      for (int i = pw; i < 16; i += 3) {
        const float* g = (i < 8) ? (xA + co + i * 256 + lane * 4)
                                 : (xBp + co + (i - 8) * 256 + lane * 4);
        gload_lds16(g, ldst + i * 256);
      }
    };
    auto produce = [&](int tc) {  // z chunk tc: xb[tc&1] -> zbuf[tc&1]
      const float* xrA = xb[tc & 1][0];
      const float* xrB = xb[tc & 1][1];
      float2* zrow = zbuf[tc & 1];
      for (int tt = tsl; tt < CH; tt += 4) {  // 8 t per lane, 2 batches each
        float zA, zB;
        {
          const float4* row4 = (const float4*)(xrA + tt * F_);
          float z0 = bcol, z1 = 0.f, z2 = 0.f, z3 = 0.f;
          #pragma unroll
          for (int j = 0; j < 16; j += 4) {   // compile-time indices only!
            float4 a0 = row4[j], a1 = row4[j + 1], a2 = row4[j + 2], a3 = row4[j + 3];
            z0 = fmaf(a0.x, wc[4*j+0], z0);  z0 = fmaf(a0.y, wc[4*j+1], z0);
            z0 = fmaf(a0.z, wc[4*j+2], z0);  z0 = fmaf(a0.w, wc[4*j+3], z0);
            z1 = fmaf(a1.x, wc[4*j+4], z1);  z1 = fmaf(a1.y, wc[4*j+5], z1);
            z1 = fmaf(a1.z, wc[4*j+6], z1);  z1 = fmaf(a1.w, wc[4*j+7], z1);
            z2 = fmaf(a2.x, wc[4*j+8], z2);  z2 = fmaf(a2.y, wc[4*j+9], z2);
            z2 = fmaf(a2.z, wc[4*j+10], z2); z2 = fmaf(a2.w, wc[4*j+11], z2);
            z3 = fmaf(a3.x, wc[4*j+12], z3); z3 = fmaf(a3.y, wc[4*j+13], z3);
            z3 = fmaf(a3.z, wc[4*j+14], z3); z3 = fmaf(a3.w, wc[4*j+15], z3);
          }
          zA = ((z0 + z1) + (z2 + z3)) * scp;
        }
        {
          const float4* row4 = (const float4*)(xrB + tt * F_);
          float z0 = bcol, z1 = 0.f, z2 = 0.f, z3 = 0.f;
          #pragma unroll
          for (int j = 0; j < 16; j += 4) {
            float4 a0 = row4[j], a1 = row4[j + 1], a2 = row4[j + 2], a3 = row4[j + 3];
            z0 = fmaf(a0.x, wc[4*j+0], z0);  z0 = fmaf(a0.y, wc[4*j+1], z0);
            z0 = fmaf(a0.z, wc[4*j+2], z0);  z0 = fmaf(a0.w, wc[4*j+3], z0);
            z1 = fmaf(a1.x, wc[4*j+4], z1);  z1 = fmaf(a1.y, wc[4*j+5], z1);
            z1 = fmaf(a1.z, wc[4*j+6], z1);  z1 = fmaf(a1.w, wc[4*j+7], z1);
            z2 = fmaf(a2.x, wc[4*j+8], z2);  z2 = fmaf(a2.y, wc[4*j+9], z2);
            z2 = fmaf(a2.z, wc[4*j+10], z2); z2 = fmaf(a2.w, wc[4*j+11], z2);
            z3 = fmaf(a3.x, wc[4*j+12], z3); z3 = fmaf(a3.y, wc[4*j+13], z3);
            z3 = fmaf(a3.z, wc[4*j+14], z3); z3 = fmaf(a3.w, wc[4*j+15], z3);
          }
          zB = ((z0 + z1) + (z2 + z3)) * scp;
        }
        if (act) zrow[tt * G_ + s] = make_float2(zA, zB);
      }
    };

    load_x(0);
    load_x(1);
    __syncthreads();  // B-pre1 (barrier drains vmcnt -> DMA visible)
    produce(0);
    __syncthreads();  // B-pre2
    for (int cc = 0; cc < NCH; ++cc) {
      if (cc + 2 < NCH) load_x(cc + 2);
      if (cc + 1 < NCH) produce(cc + 1);
      __syncthreads();  // B(cc)
    }
  }
}

extern "C" void kernel_launch(void* const* d_in, const int* in_sizes, int n_in,
                              void* d_out, int out_size, void* d_ws, size_t ws_size,
                              hipStream_t stream) {
  const float* x    = (const float*)d_in[0];  // [256,2048,64]
  const float* W    = (const float*)d_in[1];  // [64,40]
  const float* R    = (const float*)d_in[2];  // [10,40]
  const float* bias = (const float*)d_in[3];  // [40]
  const float* dw   = (const float*)d_in[4];  // [10,1]
  const float* db   = (const float*)d_in[5];  // [1]
  float* out = (float*)d_out;                 // [256]
  (void)d_ws; (void)ws_size; (void)in_sizes; (void)n_in; (void)out_size;
  lstm_fused<<<B_ / 2, 256, 0, stream>>>(x, W, R, bias, dw, db, out);
}

// Round 3
// 337.171 us; speedup vs baseline: 1.4688x; 1.4688x over previous
//
#include <hip/hip_runtime.h>

// B=256, T=2048, F=64, U=10 LSTM (Keras gates i,f,g,o; softsign cell act).
// R3: back to 1 batch/block (grid=256 == CU count; R2's grid=128 idled half
// the chip). Scan wave stripped to the bare recurrence: producers pack z for
// timestep PAIRS as float2 [t2][col]; scan preloads a whole 32-step chunk
// (16x ds_read_b64, compile-time immediate offsets) into registers after the
// barrier, then runs 32 fully-unrolled steps with ZERO per-step LDS ops,
// address math, clamps, or loop bookkeeping. Micro-savings kept: sigmoid cols
// pre-scaled by -log2e (exp2 form), shared-rcp activation, 2-chain matvec.
#define B_ 256
#define T_ 2048
#define F_ 64
#define U_ 10
#define G_ 40
#define CH 32          // timesteps per chunk
#define CH2 (CH / 2)   // float2 pairs per chunk = 16
#define NCH (T_ / CH)  // 64
#define NLOG2E (-1.44269504088896340736f)

__device__ __forceinline__ float rcp_f(float x) { return __builtin_amdgcn_rcpf(x); }
__device__ __forceinline__ float exp2_f(float x) { return __builtin_amdgcn_exp2f(x); }
__device__ __forceinline__ float rdlane_f(float v, int l) {
  return __int_as_float(__builtin_amdgcn_readlane(__float_as_int(v), l));
}
template <int CTRL>
__device__ __forceinline__ float qbcast(float v) {  // quad_perm broadcast
  return __int_as_float(
      __builtin_amdgcn_update_dpp(0, __float_as_int(v), CTRL, 0xF, 0xF, true));
}
__device__ __forceinline__ void gload_lds16(const float* g, float* l) {
  // lane i's 16B lands at l + i*16; g is per-lane (contiguous across wave)
  __builtin_amdgcn_global_load_lds(
      (const __attribute__((address_space(1))) void*)g,
      (__attribute__((address_space(3))) void*)l, 16, 0, 0);
}

__global__ __launch_bounds__(256, 1) void lstm_fused(
    const float* __restrict__ x, const float* __restrict__ W,
    const float* __restrict__ R, const float* __restrict__ bias,
    const float* __restrict__ dw, const float* __restrict__ db,
    float* __restrict__ out) {
  __shared__ float xb[2][CH * F_];    // 2 x 8 KB x-chunk buffers (DMA target)
  __shared__ float2 zb[2][CH2 * G_];  // 2 x 5 KB z pair-buffers [t2][col]
  const int b = blockIdx.x;
  const int tid = threadIdx.x;
  const int wave = tid >> 6;
  const int lane = tid & 63;
  const float* xbase = x + (size_t)b * T_ * F_;

  if (wave == 0) {
    // ---------------- scan wave ----------------
    __builtin_amdgcn_s_setprio(3);
    const int L = (lane < G_) ? lane : (G_ - 1);
    const int u = L >> 2, gate = L & 3;
    const int col = gate * U_ + u;
    const float sc = (gate == 2) ? 1.f : NLOG2E;  // sigmoid cols scaled
    float Rc[U_];
    #pragma unroll
    for (int j = 0; j < U_; ++j) Rc[j] = R[j * G_ + col] * sc;
    const float dwu = dw[u];
    const float db0 = db[0];
    float h = 0.f, c = 0.f;

    // one timestep; zseed = (pre-scaled) z for this lane's column
    auto step = [&](float zseed) {
      float h0 = rdlane_f(h, 0),  h1 = rdlane_f(h, 4),  h2 = rdlane_f(h, 8);
      float h3 = rdlane_f(h, 12), h4 = rdlane_f(h, 16), h5 = rdlane_f(h, 20);
      float h6 = rdlane_f(h, 24), h7 = rdlane_f(h, 28);
      float h8 = rdlane_f(h, 32), h9 = rdlane_f(h, 36);
      // 2-chain matvec (even/odd), minimal op count
      float z0 = fmaf(h0, Rc[0], zseed);
      float z1 = h1 * Rc[1];
      z0 = fmaf(h2, Rc[2], z0);  z1 = fmaf(h3, Rc[3], z1);
      z0 = fmaf(h4, Rc[4], z0);  z1 = fmaf(h5, Rc[5], z1);
      z0 = fmaf(h6, Rc[6], z0);  z1 = fmaf(h7, Rc[7], z1);
      z0 = fmaf(h8, Rc[8], z0);  z1 = fmaf(h9, Rc[9], z1);
      float zz = z0 + z1;
      // shared-rcp activation: sigmoid lanes zz = -log2e*z -> e^{-z}=exp2(zz)
      float e = exp2_f(zz);
      float t = (gate == 2) ? __builtin_fabsf(zz) : e;
      float r = rcp_f(1.f + t);
      float a = (gate == 2) ? zz * r : r;
      float ai = qbcast<0x00>(a);
      float af = qbcast<0x55>(a);
      float ag = qbcast<0xAA>(a);
      float ao = qbcast<0xFF>(a);
      c = fmaf(af, c, ai * ag);
      float oc = ao * c;                  // parallel with den
      float den = 1.f + __builtin_fabsf(c);
      h = oc * rcp_f(den);                // o * softsign(c)
    };

    __syncthreads();  // B-pre1: x(0),x(1) DMA complete
    __syncthreads();  // B-pre2: z(0) produced
    for (int cc = 0; cc < NCH; ++cc) {
      const float2* zp = zb[cc & 1] + L;
      float2 sd[CH2];
      #pragma unroll
      for (int k = 0; k < CH2; ++k) sd[k] = zp[k * G_];  // 16x ds_read_b64
      #pragma unroll
      for (int k = 0; k < CH2; ++k) {  // 32 steps, fully unrolled, reg-only
        step(sd[k].x);
        step(sd[k].y);
      }
      __syncthreads();  // B(cc)
    }
    // epilogue: logit = sum_u h[u]*dw[u] + db; out = sigmoid(logit)
    float p = h * dwu;
    float logit = db0;
    #pragma unroll
    for (int j = 0; j < U_; ++j) logit += rdlane_f(p, 4 * j);
    if (lane == 0) out[b] = rcp_f(1.f + __expf(-logit));
  } else {
    // ---------------- producer waves (1..3) ----------------
    const int p0 = tid - 64;                 // 0..191
    const int p = (p0 < 160) ? p0 : 159;
    const bool act = (p0 < 160);
    const int s = p % G_;                    // column slot 0..39
    const int tp = p / G_;                   // t2-slot 0..3
    const int u = s >> 2, gate = s & 3;
    const int col = gate * U_ + u;
    const int pw = wave - 1;                 // 0..2
    const float scp = (gate == 2) ? 1.f : NLOG2E;  // pre-scale sigmoid cols
    float wc[F_];
    #pragma unroll
    for (int k = 0; k < F_; ++k) wc[k] = W[k * G_ + col];
    const float bcol = bias[col];

    auto load_x = [&](int cx) {  // DMA x chunk cx -> xb[cx&1] (8 KB, 8 instr)
      const float* g = xbase + (size_t)cx * CH * F_;
      float* l = xb[cx & 1];
      for (int i = pw; i < 8; i += 3)
        gload_lds16(g + i * 256 + lane * 4, l + i * 256);
    };
    auto dot = [&](const float* xr) -> float {  // dot(x_row, W[:,col]) + bias
      const float4* row4 = (const float4*)xr;
      float z0 = bcol, z1 = 0.f, z2 = 0.f, z3 = 0.f;
      #pragma unroll
      for (int j = 0; j < 16; j += 4) {     // compile-time indices only!
        float4 a0 = row4[j], a1 = row4[j + 1], a2 = row4[j + 2], a3 = row4[j + 3];
        z0 = fmaf(a0.x, wc[4*j+0], z0);  z0 = fmaf(a0.y, wc[4*j+1], z0);
        z0 = fmaf(a0.z, wc[4*j+2], z0);  z0 = fmaf(a0.w, wc[4*j+3], z0);
        z1 = fmaf(a1.x, wc[4*j+4], z1);  z1 = fmaf(a1.y, wc[4*j+5], z1);
        z1 = fmaf(a1.z, wc[4*j+6], z1);  z1 = fmaf(a1.w, wc[4*j+7], z1);
        z2 = fmaf(a2.x, wc[4*j+8], z2);  z2 = fmaf(a2.y, wc[4*j+9], z2);
        z2 = fmaf(a2.z, wc[4*j+10], z2); z2 = fmaf(a2.w, wc[4*j+11], z2);
        z3 = fmaf(a3.x, wc[4*j+12], z3); z3 = fmaf(a3.y, wc[4*j+13], z3);
        z3 = fmaf(a3.z, wc[4*j+14], z3); z3 = fmaf(a3.w, wc[4*j+15], z3);
      }
      return ((z0 + z1) + (z2 + z3)) * scp;
    };
    auto produce = [&](int tc) {  // z chunk tc: xb[tc&1] -> zb[tc&1] (pairs)
      const float* xr = xb[tc & 1];
      float2* zrow = zb[tc & 1];
      #pragma unroll
      for (int k = 0; k < 4; ++k) {          // 4 t2-pairs per lane
        const int t2 = tp + 4 * k;           // 0..15
        float zE = dot(xr + (2 * t2) * F_);
        float zO = dot(xr + (2 * t2 + 1) * F_);
        if (act) zrow[t2 * G_ + s] = make_float2(zE, zO);
      }
    };

    load_x(0);
    load_x(1);
    __syncthreads();  // B-pre1 (barrier drains vmcnt -> DMA visible)
    produce(0);
    __syncthreads();  // B-pre2
    for (int cc = 0; cc < NCH; ++cc) {
      if (cc + 2 < NCH) load_x(cc + 2);
      if (cc + 1 < NCH) produce(cc + 1);
      __syncthreads();  // B(cc)
    }
  }
}

extern "C" void kernel_launch(void* const* d_in, const int* in_sizes, int n_in,
                              void* d_out, int out_size, void* d_ws, size_t ws_size,
                              hipStream_t stream) {
  const float* x    = (const float*)d_in[0];  // [256,2048,64]
  const float* W    = (const float*)d_in[1];  // [64,40]
  const float* R    = (const float*)d_in[2];  // [10,40]
  const float* bias = (const float*)d_in[3];  // [40]
  const float* dw   = (const float*)d_in[4];  // [10,1]
  const float* db   = (const float*)d_in[5];  // [1]
  float* out = (float*)d_out;                 // [256]
  (void)d_ws; (void)ws_size; (void)in_sizes; (void)n_in; (void)out_size;
  lstm_fused<<<B_, 256, 0, stream>>>(x, W, R, bias, dw, db, out);
}